// Round 5
// baseline (5691.236 us; speedup 1.0000x reference)
//
#include <hip/hip_runtime.h>
#include <hip/hip_bf16.h>

#define DOUT 128
#define DIN  256
#define BROWS 64            // rows per bucket (tile = 64x128 fp32 = 32 KB LDS)
#define MAXNB 1024          // scan width cap (nb = ceil(N/64) = 782 for N=50000)
#define BIN_CHUNK 4096

static __device__ __forceinline__ float bf16_to_f(unsigned short u) {
    return __uint_as_float(((unsigned)u) << 16);
}

// ======================= hV = h @ V, bf16 output ===========================
__global__ __launch_bounds__(256) void hv_gemm(const float* __restrict__ h,
                                               const float* __restrict__ V,
                                               __hip_bfloat16* __restrict__ hV,
                                               int N) {
    __shared__ __align__(16) float hsT[DOUT][36];
    int r0 = blockIdx.x * 32;
    int t = threadIdx.x, col = t & 127, g = t >> 7;
    {
        int row = t >> 3, kb = t & 7;
        int sr = min(r0 + row, N - 1);
        const float4* hr = (const float4*)(h + (size_t)sr * DOUT);
        for (int i = 0; i < 4; ++i) {
            int k4 = kb + 8 * i; float4 v4 = hr[k4]; int k = 4 * k4;
            hsT[k][row] = v4.x; hsT[k+1][row] = v4.y;
            hsT[k+2][row] = v4.z; hsT[k+3][row] = v4.w;
        }
    }
    __syncthreads();
    float acc[16];
#pragma unroll
    for (int j = 0; j < 16; ++j) acc[j] = 0.f;
    int rb = g * 16;
#pragma unroll 2
    for (int k = 0; k < DOUT; ++k) {
        float v = V[k * DOUT + col];
        const float4* hp = (const float4*)&hsT[k][rb];
        float4 a0 = hp[0], a1 = hp[1], a2 = hp[2], a3 = hp[3];
        acc[0] += v*a0.x; acc[1] += v*a0.y; acc[2] += v*a0.z; acc[3] += v*a0.w;
        acc[4] += v*a1.x; acc[5] += v*a1.y; acc[6] += v*a1.z; acc[7] += v*a1.w;
        acc[8] += v*a2.x; acc[9] += v*a2.y; acc[10]+= v*a2.z; acc[11]+= v*a2.w;
        acc[12]+= v*a3.x; acc[13]+= v*a3.y; acc[14]+= v*a3.z; acc[15]+= v*a3.w;
    }
#pragma unroll
    for (int j = 0; j < 16; ++j) {
        int r = r0 + rb + j;
        if (r < N) hV[(size_t)r * DOUT + col] = __float2bfloat16(acc[j]);
    }
}

// ======================= bucket histogram ==================================
__global__ void bucket_hist(const int* __restrict__ rows, int* __restrict__ gcnt,
                            int nE, int nb) {
    __shared__ int hc[MAXNB];
    for (int i = threadIdx.x; i < nb; i += blockDim.x) hc[i] = 0;
    __syncthreads();
    for (int i = blockIdx.x * blockDim.x + threadIdx.x; i < nE;
         i += gridDim.x * blockDim.x)
        atomicAdd(&hc[rows[i] / BROWS], 1);
    __syncthreads();
    for (int i = threadIdx.x; i < nb; i += blockDim.x)
        if (hc[i]) atomicAdd(&gcnt[i], hc[i]);
}

// ============ exclusive scan of bucket counts (single block) ===============
__global__ __launch_bounds__(1024) void scan_buckets(const int* __restrict__ gcnt,
                                                     int* __restrict__ bptr,
                                                     int* __restrict__ gcur, int nb) {
    __shared__ int sbuf[MAXNB];
    int t = threadIdx.x;
    int c = (t < nb) ? gcnt[t] : 0;
    sbuf[t] = c;
    __syncthreads();
    for (int off = 1; off < 1024; off <<= 1) {
        int v = (t >= off) ? sbuf[t - off] : 0;
        __syncthreads();
        sbuf[t] += v;
        __syncthreads();
    }
    if (t == 0) bptr[0] = 0;
    if (t < nb) { bptr[t + 1] = sbuf[t]; gcur[t] = sbuf[t] - c; }
}

// ============ bin edges into bucket-major order (LDS counting sort) ========
// record: x = (row<<16)|col  (both < 65536), y = val bits
__global__ __launch_bounds__(1024) void bin_edges(const int* __restrict__ rows,
                                                  const int* __restrict__ cols,
                                                  const float* __restrict__ vals,
                                                  int* __restrict__ gcur,
                                                  uint2* __restrict__ ecv,
                                                  int nE, int nb) {
    __shared__ uint2 srec[BIN_CHUNK];                 // 32 KB
    __shared__ int hcnt[MAXNB], sbuf[MAXNB], loff[MAXNB], lcur[MAXNB], gbase[MAXNB];
    int t = threadIdx.x;
    int base = blockIdx.x * BIN_CHUNK;
    int nvalid = min(BIN_CHUNK, nE - base);
    hcnt[t] = 0;
    __syncthreads();
    for (int j = t; j < nvalid; j += 1024)            // A: local hist
        atomicAdd(&hcnt[rows[base + j] / BROWS], 1);
    __syncthreads();
    int myc = hcnt[t];                                 // B: scan
    sbuf[t] = myc;
    __syncthreads();
    for (int off = 1; off < 1024; off <<= 1) {
        int v = (t >= off) ? sbuf[t - off] : 0;
        __syncthreads();
        sbuf[t] += v;
        __syncthreads();
    }
    int excl = sbuf[t] - myc;
    loff[t] = excl;
    lcur[t] = excl;
    if (t < nb && myc > 0) gbase[t] = atomicAdd(&gcur[t], myc);  // C: reserve
    __syncthreads();
    for (int j = t; j < nvalid; j += 1024) {          // D: place into LDS
        int i = base + j;
        unsigned r = (unsigned)rows[i];
        int b = r / BROWS;
        int slot = atomicAdd(&lcur[b], 1);
        srec[slot] = make_uint2((r << 16) | (unsigned)cols[i], __float_as_uint(vals[i]));
    }
    __syncthreads();
    for (int j = t; j < nvalid; j += 1024) {          // E: coalesced write-out
        uint2 rec = srec[j];
        int b = (int)(rec.x >> 16) / BROWS;
        ecv[gbase[b] + (j - loff[b])] = rec;
    }
}

// =============== bucketed SPMM: comb tile in LDS, fp32 atomics =============
// one block per bucket (64 rows); gathers bf16 hV rows; writes comb to out.
__global__ __launch_bounds__(512) void spmm_bucket(const int* __restrict__ bptr,
                                                   const uint2* __restrict__ ecv,
                                                   const __hip_bfloat16* __restrict__ hV,
                                                   float* __restrict__ out, int N) {
    __shared__ float tile[BROWS * DOUT];              // 32 KB
    int t = threadIdx.x;
    int b = blockIdx.x;
    {   // zero tile
        float4* tz = (float4*)tile;
        for (int j = t; j < BROWS * DOUT / 4; j += 512)
            tz[j] = make_float4(0.f, 0.f, 0.f, 0.f);
    }
    __syncthreads();
    int beg = bptr[b], end = bptr[b + 1];
    int lane = t & 63;
    for (int e = beg + (t >> 6); e < end; e += 8) {
        uint2 rec = ecv[e];
        int rloc = (int)((rec.x >> 16) & (BROWS - 1));
        int c = (int)(rec.x & 0xffffu);
        float v = __uint_as_float(rec.y);
        const ushort2* hp = (const ushort2*)(hV + (size_t)c * DOUT);
        ushort2 u = hp[lane];
        atomicAdd(&tile[rloc * DOUT + 2 * lane],     v * bf16_to_f(u.x));
        atomicAdd(&tile[rloc * DOUT + 2 * lane + 1], v * bf16_to_f(u.y));
    }
    __syncthreads();
    for (int j = t; j < BROWS * DOUT; j += 512) {     // coalesced writeback
        int gr = b * BROWS + (j >> 7);
        if (gr < N) out[(size_t)gr * DOUT + (j & 127)] = tile[j];
    }
}

// =============== epilogue: out = relu(x@W + out) in place ==================
__global__ __launch_bounds__(256) void epi_xw(const float* __restrict__ x,
                                              const float* __restrict__ W,
                                              float* __restrict__ out, int N) {
    __shared__ __align__(16) float xsT[DIN][36];      // 36.9 KB
    int r0 = blockIdx.x * 32;
    int t = threadIdx.x, col = t & 127, g = t >> 7;
    {
        int row = t >> 3, kb = t & 7;
        int sr = min(r0 + row, N - 1);
        const float4* xr = (const float4*)(x + (size_t)sr * DIN);
        for (int i = 0; i < 8; ++i) {
            int k4 = kb + 8 * i; float4 v4 = xr[k4]; int k = 4 * k4;
            xsT[k][row] = v4.x; xsT[k+1][row] = v4.y;
            xsT[k+2][row] = v4.z; xsT[k+3][row] = v4.w;
        }
    }
    __syncthreads();
    float acc[16];
#pragma unroll
    for (int j = 0; j < 16; ++j) acc[j] = 0.f;
    int rb = g * 16;
#pragma unroll 2
    for (int k = 0; k < DIN; ++k) {
        float w = W[k * DOUT + col];
        const float4* xp = (const float4*)&xsT[k][rb];
        float4 a0 = xp[0], a1 = xp[1], a2 = xp[2], a3 = xp[3];
        acc[0] += w*a0.x; acc[1] += w*a0.y; acc[2] += w*a0.z; acc[3] += w*a0.w;
        acc[4] += w*a1.x; acc[5] += w*a1.y; acc[6] += w*a1.z; acc[7] += w*a1.w;
        acc[8] += w*a2.x; acc[9] += w*a2.y; acc[10]+= w*a2.z; acc[11]+= w*a2.w;
        acc[12]+= w*a3.x; acc[13]+= w*a3.y; acc[14]+= w*a3.z; acc[15]+= w*a3.w;
    }
#pragma unroll
    for (int j = 0; j < 16; ++j) {
        int r = r0 + rb + j;
        if (r < N) {
            size_t o = (size_t)r * DOUT + col;
            out[o] = fmaxf(acc[j] + out[o], 0.f);    // thread-private RAW: safe
        }
    }
}

// ==================== fallback path (ws too small) =========================
__global__ void spmm_atomic(const int* __restrict__ rows,
                            const int* __restrict__ cols,
                            const float* __restrict__ vals,
                            const float* __restrict__ h,
                            float* __restrict__ S, int nEdges) {
    int wave = (int)((blockIdx.x * blockDim.x + threadIdx.x) >> 6);
    int lane = threadIdx.x & 63;
    if (wave >= nEdges) return;
    int r = rows[wave], c = cols[wave];
    float v = vals[wave];
    float2 hv = ((const float2*)(h + (size_t)c * DOUT))[lane];
    float* srow = S + (size_t)r * DOUT;
    atomicAdd(srow + 2 * lane,     v * hv.x);
    atomicAdd(srow + 2 * lane + 1, v * hv.y);
}

__global__ __launch_bounds__(256) void fused_out_full(const float* __restrict__ x,
                                                      const float* __restrict__ W,
                                                      const float* __restrict__ V,
                                                      float* __restrict__ out, int N) {
    __shared__ float xs[DIN];
    __shared__ float ss[DOUT];
    int r = blockIdx.x;
    int col = threadIdx.x & 127;
    if (threadIdx.x < 128) {
        float2 xv = ((const float2*)(x + (size_t)r * DIN))[col];
        xs[2 * col] = xv.x; xs[2 * col + 1] = xv.y;
        ss[col] = out[(size_t)r * DOUT + col];
    }
    __syncthreads();
    if (threadIdx.x >= 128) return;
    float acc = 0.f;
    for (int k = 0; k < DIN; ++k) acc += xs[k] * W[k * DOUT + col];
    for (int k = 0; k < DOUT; ++k) acc += ss[k] * V[k * DOUT + col];
    out[(size_t)r * DOUT + col] = fmaxf(acc, 0.f);
}

static inline size_t align256(size_t v) { return (v + 255) & ~(size_t)255; }

extern "C" void kernel_launch(void* const* d_in, const int* in_sizes, int n_in,
                              void* d_out, int out_size, void* d_ws, size_t ws_size,
                              hipStream_t stream) {
    const float* x    = (const float*)d_in[0];
    const float* h    = (const float*)d_in[1];
    const int*   rows = (const int*)d_in[2];
    const int*   cols = (const int*)d_in[3];
    const float* vals = (const float*)d_in[4];
    const float* W    = (const float*)d_in[5];
    const float* V    = (const float*)d_in[6];
    // d_in[7] (alpha): softmax over size-1 axis == 1 -> dead.

    int nE = in_sizes[2];              // D*E = 6.4M
    int N  = in_sizes[1] / DOUT;       // 50000
    int nb = (N + BROWS - 1) / BROWS;  // 782 buckets
    float* out = (float*)d_out;

    size_t o_hV   = 0;
    size_t o_gcnt = o_hV   + align256((size_t)N * DOUT * 2);
    size_t o_bptr = o_gcnt + align256((size_t)nb * 4);
    size_t o_gcur = o_bptr + align256((size_t)(nb + 1) * 4);
    size_t o_ecv  = o_gcur + align256((size_t)nb * 4);
    size_t need   = o_ecv  + (size_t)nE * 8;

    if (ws_size >= need && nb <= MAXNB) {
        char* p = (char*)d_ws;
        __hip_bfloat16* hV = (__hip_bfloat16*)(p + o_hV);
        int*   gcnt = (int*)(p + o_gcnt);
        int*   bptr = (int*)(p + o_bptr);
        int*   gcur = (int*)(p + o_gcur);
        uint2* ecv  = (uint2*)(p + o_ecv);

        hv_gemm<<<(N + 31) / 32, 256, 0, stream>>>(h, V, hV, N);
        hipMemsetAsync(gcnt, 0, (size_t)nb * 4, stream);
        bucket_hist<<<1024, 256, 0, stream>>>(rows, gcnt, nE, nb);
        scan_buckets<<<1, 1024, 0, stream>>>(gcnt, bptr, gcur, nb);
        bin_edges<<<(nE + BIN_CHUNK - 1) / BIN_CHUNK, 1024, 0, stream>>>(
            rows, cols, vals, gcur, ecv, nE, nb);
        spmm_bucket<<<nb, 512, 0, stream>>>(bptr, ecv, hV, out, N);
        epi_xw<<<(N + 31) / 32, 256, 0, stream>>>(x, W, out, N);
    } else {
        hipMemsetAsync(out, 0, (size_t)N * DOUT * 4, stream);
        spmm_atomic<<<(nE + 3) / 4, 256, 0, stream>>>(rows, cols, vals, h, out, nE);
        fused_out_full<<<N, 128, 0, stream>>>(x, W, V, out, N);
    }
}

// Round 6
// 1209.297 us; speedup vs baseline: 4.7062x; 4.7062x over previous
//
#include <hip/hip_runtime.h>
#include <hip/hip_bf16.h>

#define DOUT 128
#define DIN  256

static __device__ __forceinline__ float bf16lo_to_f(unsigned u) {
    return __uint_as_float(u << 16);
}
static __device__ __forceinline__ float bf16hi_to_f(unsigned u) {
    return __uint_as_float(u & 0xffff0000u);
}
static __device__ __forceinline__ unsigned f_to_bf16_bits(float f) {
    unsigned u = __float_as_uint(f);               // RNE round to bf16
    return (u + 0x7fffu + ((u >> 16) & 1u)) >> 16;
}

// ======================= hV = h @ V, bf16 output (validated r5) ============
__global__ __launch_bounds__(256) void hv_gemm(const float* __restrict__ h,
                                               const float* __restrict__ V,
                                               unsigned short* __restrict__ hV,
                                               int N) {
    __shared__ __align__(16) float hsT[DOUT][36];
    int r0 = blockIdx.x * 32;
    int t = threadIdx.x, col = t & 127, g = t >> 7;
    {
        int row = t >> 3, kb = t & 7;
        int sr = min(r0 + row, N - 1);
        const float4* hr = (const float4*)(h + (size_t)sr * DOUT);
        for (int i = 0; i < 4; ++i) {
            int k4 = kb + 8 * i; float4 v4 = hr[k4]; int k = 4 * k4;
            hsT[k][row] = v4.x; hsT[k+1][row] = v4.y;
            hsT[k+2][row] = v4.z; hsT[k+3][row] = v4.w;
        }
    }
    __syncthreads();
    float acc[16];
#pragma unroll
    for (int j = 0; j < 16; ++j) acc[j] = 0.f;
    int rb = g * 16;
#pragma unroll 2
    for (int k = 0; k < DOUT; ++k) {
        float v = V[k * DOUT + col];
        const float4* hp = (const float4*)&hsT[k][rb];
        float4 a0 = hp[0], a1 = hp[1], a2 = hp[2], a3 = hp[3];
        acc[0] += v*a0.x; acc[1] += v*a0.y; acc[2] += v*a0.z; acc[3] += v*a0.w;
        acc[4] += v*a1.x; acc[5] += v*a1.y; acc[6] += v*a1.z; acc[7] += v*a1.w;
        acc[8] += v*a2.x; acc[9] += v*a2.y; acc[10]+= v*a2.z; acc[11]+= v*a2.w;
        acc[12]+= v*a3.x; acc[13]+= v*a3.y; acc[14]+= v*a3.z; acc[15]+= v*a3.w;
    }
#pragma unroll
    for (int j = 0; j < 16; ++j) {
        int r = r0 + rb + j;
        if (r < N) hV[(size_t)r * DOUT + col] = (unsigned short)f_to_bf16_bits(acc[j]);
    }
}

// ======================= CSR build (validated r3/r4) =======================
__global__ void hist_rows(const int* __restrict__ rows, int* __restrict__ cnt,
                          int nE) {
    int i = blockIdx.x * blockDim.x + threadIdx.x;
    if (i < nE) atomicAdd(&cnt[rows[i]], 1);
}

__global__ __launch_bounds__(1024) void scan_blocks(const int* __restrict__ cnt,
                                                    int* __restrict__ row_ptr,
                                                    int* __restrict__ bsum, int n) {
    __shared__ int buf[1024];
    int tid = threadIdx.x;
    int i = blockIdx.x * 1024 + tid;
    buf[tid] = (i < n) ? cnt[i] : 0;
    __syncthreads();
    for (int off = 1; off < 1024; off <<= 1) {
        int t = (tid >= off) ? buf[tid - off] : 0;
        __syncthreads();
        buf[tid] += t;
        __syncthreads();
    }
    if (i < n) row_ptr[i + 1] = buf[tid];
    if (tid == 1023) bsum[blockIdx.x] = buf[1023];
}

__global__ __launch_bounds__(1024) void scan_bsum(int* __restrict__ bsum, int nb) {
    __shared__ int buf[1024];
    int t = threadIdx.x;
    buf[t] = (t < nb) ? bsum[t] : 0;
    __syncthreads();
    for (int off = 1; off < 1024; off <<= 1) {
        int v = (t >= off) ? buf[t - off] : 0;
        __syncthreads();
        buf[t] += v;
        __syncthreads();
    }
    if (t < nb) bsum[t] = buf[t];
}

__global__ __launch_bounds__(1024) void finalize_rowptr(const int* __restrict__ cnt,
                                                        const int* __restrict__ bsum,
                                                        int* __restrict__ row_ptr,
                                                        int* __restrict__ cursor, int n) {
    int tid = threadIdx.x;
    int i = blockIdx.x * 1024 + tid;
    if (i == 0) row_ptr[0] = 0;
    if (i >= n) return;
    int off = (blockIdx.x == 0) ? 0 : bsum[blockIdx.x - 1];
    int incl = row_ptr[i + 1] + off;
    row_ptr[i + 1] = incl;
    cursor[i] = incl - cnt[i];
}

// Scatter: ONE 4-byte record per edge: (col<<16) | bf16bits(val).
__global__ void scatter_edges(const int* __restrict__ rows,
                              const int* __restrict__ cols,
                              const float* __restrict__ vals,
                              int* __restrict__ cursor,
                              unsigned* __restrict__ erec, int nE) {
    int i = blockIdx.x * blockDim.x + threadIdx.x;
    if (i >= nE) return;
    int slot = atomicAdd(&cursor[rows[i]], 1);
    erec[slot] = ((unsigned)cols[i] << 16) | f_to_bf16_bits(vals[i]);
}

// ======================= SPMM (CSR, packed 4B records, bf16 hV) ============
// One wave per row; lane i owns cols {2i,2i+1} (ushort2 = one dword of hV).
__global__ void spmm_csr(const int* __restrict__ row_ptr,
                         const unsigned* __restrict__ erec,
                         const unsigned* __restrict__ hV,   // bf16x2 per dword
                         float* __restrict__ S, int n) {
    int row = blockIdx.x * 4 + (threadIdx.x >> 6);
    int lane = threadIdx.x & 63;
    if (row >= n) return;
    int beg = row_ptr[row], end = row_ptr[row + 1];
    float2 acc = {0.f, 0.f};
#pragma unroll 4
    for (int e = beg; e < end; ++e) {
        unsigned rec = erec[e];
        unsigned c = rec >> 16;
        float v = bf16lo_to_f(rec);                 // val bits in low 16
        unsigned u = hV[(size_t)c * (DOUT / 2) + lane];
        acc.x += v * bf16lo_to_f(u);
        acc.y += v * bf16hi_to_f(u);
    }
    ((float2*)(S + (size_t)row * DOUT))[lane] = acc;
}

// =============== epilogue: out = relu(x@W + out) in place (validated r5) ===
__global__ __launch_bounds__(256) void epi_xw(const float* __restrict__ x,
                                              const float* __restrict__ W,
                                              float* __restrict__ out, int N) {
    __shared__ __align__(16) float xsT[DIN][36];
    int r0 = blockIdx.x * 32;
    int t = threadIdx.x, col = t & 127, g = t >> 7;
    {
        int row = t >> 3, kb = t & 7;
        int sr = min(r0 + row, N - 1);
        const float4* xr = (const float4*)(x + (size_t)sr * DIN);
        for (int i = 0; i < 8; ++i) {
            int k4 = kb + 8 * i; float4 v4 = xr[k4]; int k = 4 * k4;
            xsT[k][row] = v4.x; xsT[k+1][row] = v4.y;
            xsT[k+2][row] = v4.z; xsT[k+3][row] = v4.w;
        }
    }
    __syncthreads();
    float acc[16];
#pragma unroll
    for (int j = 0; j < 16; ++j) acc[j] = 0.f;
    int rb = g * 16;
#pragma unroll 2
    for (int k = 0; k < DIN; ++k) {
        float w = W[k * DOUT + col];
        const float4* xp = (const float4*)&xsT[k][rb];
        float4 a0 = xp[0], a1 = xp[1], a2 = xp[2], a3 = xp[3];
        acc[0] += w*a0.x; acc[1] += w*a0.y; acc[2] += w*a0.z; acc[3] += w*a0.w;
        acc[4] += w*a1.x; acc[5] += w*a1.y; acc[6] += w*a1.z; acc[7] += w*a1.w;
        acc[8] += w*a2.x; acc[9] += w*a2.y; acc[10]+= w*a2.z; acc[11]+= w*a2.w;
        acc[12]+= w*a3.x; acc[13]+= w*a3.y; acc[14]+= w*a3.z; acc[15]+= w*a3.w;
    }
#pragma unroll
    for (int j = 0; j < 16; ++j) {
        int r = r0 + rb + j;
        if (r < N) {
            size_t o = (size_t)r * DOUT + col;
            out[o] = fmaxf(acc[j] + out[o], 0.f);
        }
    }
}

// ==================== fallback path (ws too small / N too big) =============
__global__ void spmm_atomic(const int* __restrict__ rows,
                            const int* __restrict__ cols,
                            const float* __restrict__ vals,
                            const float* __restrict__ h,
                            float* __restrict__ S, int nEdges) {
    int wave = (int)((blockIdx.x * blockDim.x + threadIdx.x) >> 6);
    int lane = threadIdx.x & 63;
    if (wave >= nEdges) return;
    int r = rows[wave], c = cols[wave];
    float v = vals[wave];
    float2 hv = ((const float2*)(h + (size_t)c * DOUT))[lane];
    float* srow = S + (size_t)r * DOUT;
    atomicAdd(srow + 2 * lane,     v * hv.x);
    atomicAdd(srow + 2 * lane + 1, v * hv.y);
}

__global__ __launch_bounds__(256) void fused_out_full(const float* __restrict__ x,
                                                      const float* __restrict__ W,
                                                      const float* __restrict__ V,
                                                      float* __restrict__ out, int N) {
    __shared__ float xs[DIN];
    __shared__ float ss[DOUT];
    int r = blockIdx.x;
    int col = threadIdx.x & 127;
    if (threadIdx.x < 128) {
        float2 xv = ((const float2*)(x + (size_t)r * DIN))[col];
        xs[2 * col] = xv.x; xs[2 * col + 1] = xv.y;
        ss[col] = out[(size_t)r * DOUT + col];
    }
    __syncthreads();
    if (threadIdx.x >= 128) return;
    float acc = 0.f;
    for (int k = 0; k < DIN; ++k) acc += xs[k] * W[k * DOUT + col];
    for (int k = 0; k < DOUT; ++k) acc += ss[k] * V[k * DOUT + col];
    out[(size_t)r * DOUT + col] = fmaxf(acc, 0.f);
}

static inline size_t align256(size_t v) { return (v + 255) & ~(size_t)255; }

extern "C" void kernel_launch(void* const* d_in, const int* in_sizes, int n_in,
                              void* d_out, int out_size, void* d_ws, size_t ws_size,
                              hipStream_t stream) {
    const float* x    = (const float*)d_in[0];
    const float* h    = (const float*)d_in[1];
    const int*   rows = (const int*)d_in[2];
    const int*   cols = (const int*)d_in[3];
    const float* vals = (const float*)d_in[4];
    const float* W    = (const float*)d_in[5];
    const float* V    = (const float*)d_in[6];
    // d_in[7] (alpha): softmax over a size-1 axis == 1 -> dead.

    int nE = in_sizes[2];              // D*E = 6.4M
    int N  = in_sizes[1] / DOUT;       // 50000
    float* out = (float*)d_out;

    int nScanBlocks = (N + 1023) / 1024;   // 49

    // ws: hV[N*128 bf16] | cnt[N] | row_ptr[N+1] | cursor[N] | bsum[1024] | erec[nE u32]
    size_t o_hV   = 0;
    size_t o_cnt  = o_hV  + align256((size_t)N * DOUT * 2);
    size_t o_rp   = o_cnt + align256((size_t)N * 4);
    size_t o_cur  = o_rp  + align256((size_t)(N + 1) * 4);
    size_t o_bsum = o_cur + align256((size_t)N * 4);
    size_t o_erec = o_bsum + align256(1024 * 4);
    size_t need   = o_erec + (size_t)nE * 4;

    if (ws_size >= need && N < 65536 && nScanBlocks <= 1024) {
        char* p = (char*)d_ws;
        unsigned short* hV = (unsigned short*)(p + o_hV);
        int*      cnt     = (int*)(p + o_cnt);
        int*      row_ptr = (int*)(p + o_rp);
        int*      cursor  = (int*)(p + o_cur);
        int*      bsum    = (int*)(p + o_bsum);
        unsigned* erec    = (unsigned*)(p + o_erec);

        hv_gemm<<<(N + 31) / 32, 256, 0, stream>>>(h, V, hV, N);
        hipMemsetAsync(cnt, 0, (size_t)N * 4, stream);
        hist_rows<<<(nE + 255) / 256, 256, 0, stream>>>(rows, cnt, nE);
        scan_blocks<<<nScanBlocks, 1024, 0, stream>>>(cnt, row_ptr, bsum, N);
        scan_bsum<<<1, 1024, 0, stream>>>(bsum, nScanBlocks);
        finalize_rowptr<<<nScanBlocks, 1024, 0, stream>>>(cnt, bsum, row_ptr,
                                                          cursor, N);
        scatter_edges<<<(nE + 255) / 256, 256, 0, stream>>>(rows, cols, vals,
                                                            cursor, erec, nE);
        spmm_csr<<<(N + 3) / 4, 256, 0, stream>>>(row_ptr, erec,
                                                  (const unsigned*)hV, out, N);
        epi_xw<<<(N + 31) / 32, 256, 0, stream>>>(x, W, out, N);
    } else {
        hipMemsetAsync(out, 0, (size_t)N * DOUT * 4, stream);
        spmm_atomic<<<(nE + 3) / 4, 256, 0, stream>>>(rows, cols, vals, h, out, nE);
        fused_out_full<<<N, 128, 0, stream>>>(x, W, V, out, N);
    }
}

// Round 7
// 1130.260 us; speedup vs baseline: 5.0353x; 1.0699x over previous
//
#include <hip/hip_runtime.h>
#include <hip/hip_bf16.h>

#define DOUT 128
#define DIN  256
#define BROWS 128           // rows per bucket
#define MAXNB 1024          // bucket-scan width cap (nb = ceil(N/128) = 391)
#define BIN_CHUNK 4096      // edges per bin_edges block
#define SCHUNK 8192         // edges per spmm LDS chunk (32 KB records)

static __device__ __forceinline__ float bf16lo_to_f(unsigned u) {
    return __uint_as_float(u << 16);
}
static __device__ __forceinline__ float bf16hi_to_f(unsigned u) {
    return __uint_as_float(u & 0xffff0000u);
}
static __device__ __forceinline__ unsigned f_to_bf16_bits(float f) {
    unsigned u = __float_as_uint(f);               // RNE round to bf16
    return (u + 0x7fffu + ((u >> 16) & 1u)) >> 16;
}

// ======================= hV = h @ V, bf16 output (validated r5/r6) =========
__global__ __launch_bounds__(256) void hv_gemm(const float* __restrict__ h,
                                               const float* __restrict__ V,
                                               unsigned short* __restrict__ hV,
                                               int N) {
    __shared__ __align__(16) float hsT[DOUT][36];
    int r0 = blockIdx.x * 32;
    int t = threadIdx.x, col = t & 127, g = t >> 7;
    {
        int row = t >> 3, kb = t & 7;
        int sr = min(r0 + row, N - 1);
        const float4* hr = (const float4*)(h + (size_t)sr * DOUT);
        for (int i = 0; i < 4; ++i) {
            int k4 = kb + 8 * i; float4 v4 = hr[k4]; int k = 4 * k4;
            hsT[k][row] = v4.x; hsT[k+1][row] = v4.y;
            hsT[k+2][row] = v4.z; hsT[k+3][row] = v4.w;
        }
    }
    __syncthreads();
    float acc[16];
#pragma unroll
    for (int j = 0; j < 16; ++j) acc[j] = 0.f;
    int rb = g * 16;
#pragma unroll 2
    for (int k = 0; k < DOUT; ++k) {
        float v = V[k * DOUT + col];
        const float4* hp = (const float4*)&hsT[k][rb];
        float4 a0 = hp[0], a1 = hp[1], a2 = hp[2], a3 = hp[3];
        acc[0] += v*a0.x; acc[1] += v*a0.y; acc[2] += v*a0.z; acc[3] += v*a0.w;
        acc[4] += v*a1.x; acc[5] += v*a1.y; acc[6] += v*a1.z; acc[7] += v*a1.w;
        acc[8] += v*a2.x; acc[9] += v*a2.y; acc[10]+= v*a2.z; acc[11]+= v*a2.w;
        acc[12]+= v*a3.x; acc[13]+= v*a3.y; acc[14]+= v*a3.z; acc[15]+= v*a3.w;
    }
#pragma unroll
    for (int j = 0; j < 16; ++j) {
        int r = r0 + rb + j;
        if (r < N) hV[(size_t)r * DOUT + col] = (unsigned short)f_to_bf16_bits(acc[j]);
    }
}

// ======================= bucket histogram (validated r5) ===================
__global__ void bucket_hist(const int* __restrict__ rows, int* __restrict__ gcnt,
                            int nE, int nb) {
    __shared__ int hc[MAXNB];
    for (int i = threadIdx.x; i < nb; i += blockDim.x) hc[i] = 0;
    __syncthreads();
    for (int i = blockIdx.x * blockDim.x + threadIdx.x; i < nE;
         i += gridDim.x * blockDim.x)
        atomicAdd(&hc[rows[i] / BROWS], 1);
    __syncthreads();
    for (int i = threadIdx.x; i < nb; i += blockDim.x)
        if (hc[i]) atomicAdd(&gcnt[i], hc[i]);
}

// ============ exclusive scan of bucket counts (validated r5) ===============
__global__ __launch_bounds__(1024) void scan_buckets(const int* __restrict__ gcnt,
                                                     int* __restrict__ bptr,
                                                     int* __restrict__ gcur, int nb) {
    __shared__ int sbuf[MAXNB];
    int t = threadIdx.x;
    int c = (t < nb) ? gcnt[t] : 0;
    sbuf[t] = c;
    __syncthreads();
    for (int off = 1; off < 1024; off <<= 1) {
        int v = (t >= off) ? sbuf[t - off] : 0;
        __syncthreads();
        sbuf[t] += v;
        __syncthreads();
    }
    if (t == 0) bptr[0] = 0;
    if (t < nb) { bptr[t + 1] = sbuf[t]; gcur[t] = sbuf[t] - c; }
}

// ===== bin edges into bucket-major order, LDS counting sort (valid. r5) ====
// record: x = (row<<16)|col  (both < 65536), y = fp32 val bits
__global__ __launch_bounds__(1024) void bin_edges(const int* __restrict__ rows,
                                                  const int* __restrict__ cols,
                                                  const float* __restrict__ vals,
                                                  int* __restrict__ gcur,
                                                  uint2* __restrict__ ecv,
                                                  int nE, int nb) {
    __shared__ uint2 srec[BIN_CHUNK];                 // 32 KB
    __shared__ int hcnt[MAXNB], sbuf[MAXNB], loff[MAXNB], lcur[MAXNB], gbase[MAXNB];
    int t = threadIdx.x;
    int base = blockIdx.x * BIN_CHUNK;
    int nvalid = min(BIN_CHUNK, nE - base);
    hcnt[t] = 0;
    __syncthreads();
    for (int j = t; j < nvalid; j += 1024)            // A: local hist
        atomicAdd(&hcnt[rows[base + j] / BROWS], 1);
    __syncthreads();
    int myc = hcnt[t];                                 // B: scan
    sbuf[t] = myc;
    __syncthreads();
    for (int off = 1; off < 1024; off <<= 1) {
        int v = (t >= off) ? sbuf[t - off] : 0;
        __syncthreads();
        sbuf[t] += v;
        __syncthreads();
    }
    int excl = sbuf[t] - myc;
    loff[t] = excl;
    lcur[t] = excl;
    if (t < nb && myc > 0) gbase[t] = atomicAdd(&gcur[t], myc);  // C: reserve
    __syncthreads();
    for (int j = t; j < nvalid; j += 1024) {          // D: place into LDS
        int i = base + j;
        unsigned r = (unsigned)rows[i];
        int b = r / BROWS;
        int slot = atomicAdd(&lcur[b], 1);
        srec[slot] = make_uint2((r << 16) | (unsigned)cols[i], __float_as_uint(vals[i]));
    }
    __syncthreads();
    for (int j = t; j < nvalid; j += 1024) {          // E: coalesced write-out
        uint2 rec = srec[j];
        int b = (int)(rec.x >> 16) / BROWS;
        ecv[gbase[b] + (j - loff[b])] = rec;
    }
}

// ============== SPMM on buckets: row-sort chunk in LDS, reg accumulate =====
// One block (512 thr, 8 waves) per bucket of 128 rows. Wave w owns rows
// w*16..w*16+15; lane i owns col pair {2i,2i+1}. Per chunk: 128-counter LDS
// counting sort (cheap-class atomics), then per-row register accumulation —
// NO per-edge data atomics anywhere.
__global__ __launch_bounds__(512) void spmm_sorted(const int* __restrict__ bptr,
                                                   const uint2* __restrict__ ecv,
                                                   const unsigned* __restrict__ hV,
                                                   float* __restrict__ out, int N) {
    __shared__ unsigned srec[SCHUNK];                 // (col<<16)|bf16(val), 32 KB
    __shared__ int rcnt[BROWS], sbuf[BROWS], rptr[BROWS + 1], rcur[BROWS];
    int t = threadIdx.x;
    int b = blockIdx.x;
    int wave = t >> 6, lane = t & 63;
    int beg = bptr[b], end = bptr[b + 1];

    float2 acc[16];
#pragma unroll
    for (int j = 0; j < 16; ++j) acc[j] = make_float2(0.f, 0.f);

    for (int cb = beg; cb < end; cb += SCHUNK) {
        int nval = min(SCHUNK, end - cb);
        if (t < BROWS) rcnt[t] = 0;
        __syncthreads();
        for (int j = t; j < nval; j += 512) {          // hist by local row
            unsigned rx = ecv[cb + j].x;
            atomicAdd(&rcnt[(rx >> 16) & (BROWS - 1)], 1);
        }
        __syncthreads();
        int c = (t < BROWS) ? rcnt[t] : 0;             // scan
        if (t < BROWS) sbuf[t] = c;
        __syncthreads();
        for (int off = 1; off < BROWS; off <<= 1) {
            int add = (t < BROWS && t >= off) ? sbuf[t - off] : 0;
            __syncthreads();
            if (t < BROWS) sbuf[t] += add;
            __syncthreads();
        }
        if (t == 0) rptr[0] = 0;
        if (t < BROWS) { rptr[t + 1] = sbuf[t]; rcur[t] = sbuf[t] - c; }
        __syncthreads();
        for (int j = t; j < nval; j += 512) {          // place sorted-by-row
            uint2 rec = ecv[cb + j];
            int rloc = (int)(rec.x >> 16) & (BROWS - 1);
            int slot = atomicAdd(&rcur[rloc], 1);
            srec[slot] = ((rec.x & 0xffffu) << 16) |
                         f_to_bf16_bits(__uint_as_float(rec.y));
        }
        __syncthreads();
        // compute: wave-uniform segment bounds, LDS broadcast reads
#pragma unroll
        for (int rr = 0; rr < 16; ++rr) {
            int rloc = wave * 16 + rr;
            int s = rptr[rloc], e2 = rptr[rloc + 1];
            float2 a = acc[rr];
            for (int e = s; e < e2; ++e) {
                unsigned r4 = srec[e];
                float v = bf16lo_to_f(r4);
                unsigned u = hV[(size_t)(r4 >> 16) * (DOUT / 2) + lane];
                a.x += v * bf16lo_to_f(u);
                a.y += v * bf16hi_to_f(u);
            }
            acc[rr] = a;
        }
        __syncthreads();
    }
#pragma unroll
    for (int rr = 0; rr < 16; ++rr) {                  // coalesced writeback
        int gr = b * BROWS + wave * 16 + rr;
        if (gr < N) ((float2*)(out + (size_t)gr * DOUT))[lane] = acc[rr];
    }
}

// =============== epilogue: out = relu(x@W + out) in place (valid. r5/r6) ===
__global__ __launch_bounds__(256) void epi_xw(const float* __restrict__ x,
                                              const float* __restrict__ W,
                                              float* __restrict__ out, int N) {
    __shared__ __align__(16) float xsT[DIN][36];
    int r0 = blockIdx.x * 32;
    int t = threadIdx.x, col = t & 127, g = t >> 7;
    {
        int row = t >> 3, kb = t & 7;
        int sr = min(r0 + row, N - 1);
        const float4* xr = (const float4*)(x + (size_t)sr * DIN);
        for (int i = 0; i < 8; ++i) {
            int k4 = kb + 8 * i; float4 v4 = xr[k4]; int k = 4 * k4;
            xsT[k][row] = v4.x; xsT[k+1][row] = v4.y;
            xsT[k+2][row] = v4.z; xsT[k+3][row] = v4.w;
        }
    }
    __syncthreads();
    float acc[16];
#pragma unroll
    for (int j = 0; j < 16; ++j) acc[j] = 0.f;
    int rb = g * 16;
#pragma unroll 2
    for (int k = 0; k < DIN; ++k) {
        float w = W[k * DOUT + col];
        const float4* xp = (const float4*)&xsT[k][rb];
        float4 a0 = xp[0], a1 = xp[1], a2 = xp[2], a3 = xp[3];
        acc[0] += w*a0.x; acc[1] += w*a0.y; acc[2] += w*a0.z; acc[3] += w*a0.w;
        acc[4] += w*a1.x; acc[5] += w*a1.y; acc[6] += w*a1.z; acc[7] += w*a1.w;
        acc[8] += w*a2.x; acc[9] += w*a2.y; acc[10]+= w*a2.z; acc[11]+= w*a2.w;
        acc[12]+= w*a3.x; acc[13]+= w*a3.y; acc[14]+= w*a3.z; acc[15]+= w*a3.w;
    }
#pragma unroll
    for (int j = 0; j < 16; ++j) {
        int r = r0 + rb + j;
        if (r < N) {
            size_t o = (size_t)r * DOUT + col;
            out[o] = fmaxf(acc[j] + out[o], 0.f);
        }
    }
}

// ==================== fallback path (ws too small / N too big) =============
__global__ void spmm_atomic(const int* __restrict__ rows,
                            const int* __restrict__ cols,
                            const float* __restrict__ vals,
                            const float* __restrict__ h,
                            float* __restrict__ S, int nEdges) {
    int wave = (int)((blockIdx.x * blockDim.x + threadIdx.x) >> 6);
    int lane = threadIdx.x & 63;
    if (wave >= nEdges) return;
    int r = rows[wave], c = cols[wave];
    float v = vals[wave];
    float2 hv = ((const float2*)(h + (size_t)c * DOUT))[lane];
    float* srow = S + (size_t)r * DOUT;
    atomicAdd(srow + 2 * lane,     v * hv.x);
    atomicAdd(srow + 2 * lane + 1, v * hv.y);
}

__global__ __launch_bounds__(256) void fused_out_full(const float* __restrict__ x,
                                                      const float* __restrict__ W,
                                                      const float* __restrict__ V,
                                                      float* __restrict__ out, int N) {
    __shared__ float xs[DIN];
    __shared__ float ss[DOUT];
    int r = blockIdx.x;
    int col = threadIdx.x & 127;
    if (threadIdx.x < 128) {
        float2 xv = ((const float2*)(x + (size_t)r * DIN))[col];
        xs[2 * col] = xv.x; xs[2 * col + 1] = xv.y;
        ss[col] = out[(size_t)r * DOUT + col];
    }
    __syncthreads();
    if (threadIdx.x >= 128) return;
    float acc = 0.f;
    for (int k = 0; k < DIN; ++k) acc += xs[k] * W[k * DOUT + col];
    for (int k = 0; k < DOUT; ++k) acc += ss[k] * V[k * DOUT + col];
    out[(size_t)r * DOUT + col] = fmaxf(acc, 0.f);
}

static inline size_t align256(size_t v) { return (v + 255) & ~(size_t)255; }

extern "C" void kernel_launch(void* const* d_in, const int* in_sizes, int n_in,
                              void* d_out, int out_size, void* d_ws, size_t ws_size,
                              hipStream_t stream) {
    const float* x    = (const float*)d_in[0];
    const float* h    = (const float*)d_in[1];
    const int*   rows = (const int*)d_in[2];
    const int*   cols = (const int*)d_in[3];
    const float* vals = (const float*)d_in[4];
    const float* W    = (const float*)d_in[5];
    const float* V    = (const float*)d_in[6];
    // d_in[7] (alpha): softmax over a size-1 axis == 1 -> dead.

    int nE = in_sizes[2];              // D*E = 6.4M
    int N  = in_sizes[1] / DOUT;       // 50000
    int nb = (N + BROWS - 1) / BROWS;  // 391 buckets
    float* out = (float*)d_out;

    // ws: hV[N*128 bf16] | gcnt[nb] | bptr[nb+1] | gcur[nb] | ecv[nE uint2]
    size_t o_hV   = 0;
    size_t o_gcnt = o_hV   + align256((size_t)N * DOUT * 2);
    size_t o_bptr = o_gcnt + align256((size_t)nb * 4);
    size_t o_gcur = o_bptr + align256((size_t)(nb + 1) * 4);
    size_t o_ecv  = o_gcur + align256((size_t)nb * 4);
    size_t need   = o_ecv  + (size_t)nE * 8;

    if (ws_size >= need && N < 65536 && nb <= MAXNB) {
        char* p = (char*)d_ws;
        unsigned short* hV = (unsigned short*)(p + o_hV);
        int*   gcnt = (int*)(p + o_gcnt);
        int*   bptr = (int*)(p + o_bptr);
        int*   gcur = (int*)(p + o_gcur);
        uint2* ecv  = (uint2*)(p + o_ecv);

        hv_gemm<<<(N + 31) / 32, 256, 0, stream>>>(h, V, hV, N);
        hipMemsetAsync(gcnt, 0, (size_t)nb * 4, stream);
        bucket_hist<<<1024, 256, 0, stream>>>(rows, gcnt, nE, nb);
        scan_buckets<<<1, 1024, 0, stream>>>(gcnt, bptr, gcur, nb);
        bin_edges<<<(nE + BIN_CHUNK - 1) / BIN_CHUNK, 1024, 0, stream>>>(
            rows, cols, vals, gcur, ecv, nE, nb);
        spmm_sorted<<<nb, 512, 0, stream>>>(bptr, ecv, (const unsigned*)hV, out, N);
        epi_xw<<<(N + 31) / 32, 256, 0, stream>>>(x, W, out, N);
    } else {
        hipMemsetAsync(out, 0, (size_t)N * DOUT * 4, stream);
        spmm_atomic<<<(nE + 3) / 4, 256, 0, stream>>>(rows, cols, vals, h, out, nE);
        fused_out_full<<<N, 128, 0, stream>>>(x, W, V, out, N);
    }
}